// Round 1
// baseline (127.183 us; speedup 1.0000x reference)
//
#include <hip/hip_runtime.h>
#include <hip/hip_fp8.h>

#define BB 8
#define NN 4096
#define MM 4096
#define DD 128

typedef float f32x4  __attribute__((ext_vector_type(4)));
typedef float f32x16 __attribute__((ext_vector_type(16)));
typedef int   i32x4  __attribute__((ext_vector_type(4)));
typedef int   i32x8  __attribute__((ext_vector_type(8)));

// ---------------------------------------------------------------------------
// R20: switch the inner product to the MX-scaled MFMA
// v_mfma_scale_f32_32x32x64_f8f6f4 (fp8 fmt, identity scale 127 = 2^0).
// Same 32n x 32m x 128k tile per wave-batch, but 2 MFMA instructions instead
// of 16 (K=64 each), at 2x the per-FLOP matrix rate (4686 vs ~2100 TF).
// Matrix-pipe demand per wave-batch: ~310 -> ~34 cyc/SIMD; 14 fewer issue
// slots per batch out of the measured ~78 (prior session: issue-bound 26+52).
//
// Fragment layout (32x32x64, fp8): operand lane l holds row/col = l&31,
// k = (l>>5)*32 + byte(0..31) across 8 VGPRs. prep stores each row's 128
// k-bytes as: group(row>>5)*4096 + (k>>6)*2048 + ((k>>5)&1)*1024
//            + (row&31)*32 + (k&31).
// A and B use identical storage, so within-operand k-permutation risk
// cancels in the dot product.
//
// C/D layout (HW-verified, shape-determined): col = lane&31,
// row = (reg&3) + 8*(reg>>2) + 4*(lane>>5).
//
// R19 trick retained: prep stores HALF-norms (x2/2, y2/2) and NEGATED y in
// fp8; seeding acc with x2/2 + y2/2 makes the MFMA emit acc = sq/2 directly.
//
// LESSONS: merged finalize in the 4096-block main always regresses
// (R11/12/15/16); cooperative launch fails (R14); explicit pipelining loses
// to TLP (R3/4/8/11); balanced per-XCD patch keeps the working set under the
// 4MB XCD L2 (R17, FETCH 51->13MB).
// ---------------------------------------------------------------------------

// Prep: one thread per 8 consecutive k of one row (16 threads/row).
// 2x float4 loads, 4x HW cvt_pk_fp8 (y negated), ONE 8B fragment-ordered
// store, 4-level shfl HALF-norm reduce. Also inits fwd/bsum/fsum/counter.
__global__ __launch_bounds__(256)
void prep_all(const float* __restrict__ x, const float* __restrict__ y,
              unsigned char* __restrict__ xq, unsigned char* __restrict__ yq,
              float* __restrict__ x2, float* __restrict__ y2,
              unsigned int* __restrict__ fwd, float* __restrict__ bsum,
              float* __restrict__ fsum, unsigned int* __restrict__ counter) {
    int gtid = blockIdx.x * blockDim.x + threadIdx.x;
    if (gtid < BB * MM) fwd[gtid] = 0x7f800000u;  // +inf bits
    if (gtid == 0) { *bsum = 0.0f; *fsum = 0.0f; *counter = 0u; }

    int row  = gtid >> 4;          // one row per 16 threads
    int sub8 = gtid & 15;          // 8-float chunk within the row
    const float* src;
    unsigned char* dst;
    float* sq;
    float sgn;
    if (row < BB * NN) {
        src = x; dst = xq; sq = x2; sgn = 1.0f;
    } else {
        src = y; dst = yq; sq = y2; sgn = -1.0f;  // negate y: acc = sq/2
        row -= BB * NN;
    }
    const f32x4* base = (const f32x4*)(src + (size_t)row * DD + sub8 * 8);
    f32x4 v0 = base[0];
    f32x4 v1 = base[1];
    float s = v0.x * v0.x + v0.y * v0.y + v0.z * v0.z + v0.w * v0.w
            + v1.x * v1.x + v1.y * v1.y + v1.z * v1.z + v1.w * v1.w;

    unsigned int d0 = (unsigned int)__builtin_amdgcn_cvt_pk_fp8_f32(sgn * v0.x, sgn * v0.y, 0, false);
    d0 = (unsigned int)__builtin_amdgcn_cvt_pk_fp8_f32(sgn * v0.z, sgn * v0.w, (int)d0, true);
    unsigned int d1 = (unsigned int)__builtin_amdgcn_cvt_pk_fp8_f32(sgn * v1.x, sgn * v1.y, 0, false);
    d1 = (unsigned int)__builtin_amdgcn_cvt_pk_fp8_f32(sgn * v1.z, sgn * v1.w, (int)d1, true);

    // k = sub8*8 + (0..7):
    //   instr = k>>6, khalf = (k>>5)&1, j = k&31 (contiguous 8 bytes)
    int instr = sub8 >> 3;
    int kh    = (sub8 >> 2) & 1;
    int jq    = sub8 & 3;
    size_t dstoff = (size_t)(row >> 5) * 4096 + (size_t)instr * 2048
                  + (size_t)kh * 1024 + (size_t)(row & 31) * 32 + (size_t)jq * 8;
    uint2 d;
    d.x = d0;
    d.y = d1;
    *(uint2*)(dst + dstoff) = d;

    #pragma unroll
    for (int m = 8; m; m >>= 1) s += __shfl_xor(s, m, 64);  // 16-lane group
    if (sub8 == 0) sq[row] = 0.5f * s;  // HALF-norm
}

// ---------------------------------------------------------------------------
// Main: R17 structure (fence-free, balanced XCD patch), MX MFMA inner loop.
// Accumulator SEEDED with x2/2+y2/2 so acc = sq/2; sq = 2*acc folded into
// the final sqrt sites.
// ---------------------------------------------------------------------------
__global__ __launch_bounds__(256, 4)
void chamfer_main(const unsigned char* __restrict__ xq, const unsigned char* __restrict__ yq,
                  const float* __restrict__ x2, const float* __restrict__ y2,
                  unsigned int* __restrict__ fwd, float* __restrict__ bpart) {
    __shared__ float x2s[BB][128];          // 4 KB (half-norms)
    __shared__ float y2s[BB][32];           // 1 KB (half-norms)
    __shared__ unsigned int fbuf[BB][32];   // 1 KB (min sq/2 bits)
    __shared__ float red[4];

    const int tid   = threadIdx.x;
    const int lane  = tid & 63;
    const int wave  = tid >> 6;
    const int lhalf = lane >> 5;   // K-half for operand frags; +4 row off for C/D
    const int l31   = lane & 31;

    const int id  = blockIdx.x;
    const int xcd = id & 7;
    const int j   = id >> 3;                  // 0..511
    const int nb  = (xcd >> 1) * 8 + (j & 7); // 0..31 (128 n each)
    const int mb  = (xcd & 1) * 64 + (j >> 3);// 0..127 (32 m each)
    const int n0b = nb * 128;
    const int n0w = n0b + wave * 32;
    const int m0  = mb * 32;

    // operand fragment base: group*4096 + (lane>>5)*1024 + (lane&31)*32
    const size_t laneoff = (size_t)lhalf * 1024 + (size_t)l31 * 32;
    const unsigned char* xbase = xq + (size_t)(n0w >> 5) * 4096 + laneoff;
    const unsigned char* ybase = yq + (size_t)mb * 4096 + laneoff;

    for (int i = tid; i < BB * 128; i += 256)
        x2s[i >> 7][i & 127] = x2[(size_t)(i >> 7) * NN + n0b + (i & 127)];
    if (tid < BB * 32) {
        y2s[tid >> 5][tid & 31] = y2[(size_t)(tid >> 5) * MM + m0 + (tid & 31)];
        ((unsigned int*)fbuf)[tid] = 0x7f800000u;
    }
    __syncthreads();

    i32x4 fx[2][2][2], fy[2][2][2];  // [buf][instr(K64)][16B half]
    auto loadb = [&](int b, int s) {
        const unsigned char* xb = xbase + ((size_t)b << 19);  // b*128 groups*4KB
        const unsigned char* yb = ybase + ((size_t)b << 19);
        #pragma unroll
        for (int i = 0; i < 2; ++i)
            #pragma unroll
            for (int hh = 0; hh < 2; ++hh) {
                fx[s][i][hh] = *(const i32x4*)(xb + i * 2048 + hh * 16);
                fy[s][i][hh] = *(const i32x4*)(yb + i * 2048 + hh * 16);
            }
    };
    loadb(0, 0);

    const float INF = __builtin_inff();
    float bmin[16];  // running min of acc = sq/2 over batches
    #pragma unroll
    for (int r = 0; r < 16; ++r) bmin[r] = INF;

    #pragma unroll 2
    for (int b = 0; b < BB; ++b) {
        const int cur = b & 1;
        if (b < BB - 1) loadb(b + 1, cur ^ 1);  // the ONLY vmem in the loop

        // seed acc with (x2+y2)/2 -> MFMA (with -y fp8) yields acc = sq/2
        // C/D: col = l31, row = (r&3) + 8*(r>>2) + 4*lhalf
        float y2v = y2s[b][l31];
        f32x16 acc;
        #pragma unroll
        for (int q = 0; q < 4; ++q) {
            f32x4 xv = *(const f32x4*)&x2s[b][wave * 32 + lhalf * 4 + q * 8];
            #pragma unroll
            for (int e = 0; e < 4; ++e)
                acc[q * 4 + e] = xv[e] + y2v;
        }

        #pragma unroll
        for (int i = 0; i < 2; ++i) {
            i32x8 av = __builtin_shufflevector(fx[cur][i][0], fx[cur][i][1],
                                               0, 1, 2, 3, 4, 5, 6, 7);
            i32x8 bv = __builtin_shufflevector(fy[cur][i][0], fy[cur][i][1],
                                               0, 1, 2, 3, 4, 5, 6, 7);
            // fmt 0 = fp8 e4m3 for A and B; E8M0 scale 127 -> 2^0 = 1.0
            acc = __builtin_amdgcn_mfma_scale_f32_32x32x64_f8f6f4(
                av, bv, acc, 0, 0, 0, 127, 0, 127);
        }

        // epilogue: pure fmin (acc IS sq/2); one fwd atomic per lane
        float fm = INF;
        #pragma unroll
        for (int r = 0; r < 16; ++r) {
            bmin[r] = fminf(bmin[r], acc[r]);
            fm      = fminf(fm, acc[r]);
        }
        // clamp >=0 so uint ordering == float ordering; lanes l/l+32 share
        // an address (2-way): no-return ds_min, pipelined
        atomicMin(&fbuf[b][l31], __float_as_uint(fmaxf(fm, 0.0f)));
    }
    __syncthreads();

    // flush forward mins (values are sq/2; finalize applies the 2x)
    {
        int b = tid >> 5, c = tid & 31;
        atomicMin(&fwd[(size_t)b * MM + m0 + c], fbuf[b][c]);
    }

    // backward: sqrt(2 * clamp(min sq/2)), block-reduce, one store/block
    float s = 0.0f;
    #pragma unroll
    for (int r = 0; r < 16; ++r)
        s += sqrtf(2.0f * fmaxf(bmin[r], 0.0f));
    #pragma unroll
    for (int off = 32; off; off >>= 1) s += __shfl_down(s, off, 64);
    if (lane == 0) red[wave] = s;
    __syncthreads();
    if (tid == 0) bpart[id] = red[0] + red[1] + red[2] + red[3];
}

// Finalize: 32 blocks x 256 threads (fences live here, paid 32x not 4096x).
// fwd holds min sq/2 -> dist = sqrt(2*v).
__global__ __launch_bounds__(256)
void finalize_kernel(const unsigned int* __restrict__ fwd,
                     const float* __restrict__ bpart,
                     float* __restrict__ bsum, float* __restrict__ fsum,
                     unsigned int* __restrict__ counter, float* __restrict__ out) {
    __shared__ float redf[4], redb[4];
    __shared__ int isLast;
    const int tid = threadIdx.x, lane = tid & 63, wave = tid >> 6;
    const int gtid = blockIdx.x * 256 + tid;
    uint4 u = ((const uint4*)fwd)[gtid];
    float sf = sqrtf(2.0f * __uint_as_float(u.x)) + sqrtf(2.0f * __uint_as_float(u.y)) +
               sqrtf(2.0f * __uint_as_float(u.z)) + sqrtf(2.0f * __uint_as_float(u.w));
    float sb = (gtid < 4096) ? bpart[gtid] : 0.0f;
    #pragma unroll
    for (int off = 32; off; off >>= 1) {
        sf += __shfl_down(sf, off, 64);
        sb += __shfl_down(sb, off, 64);
    }
    if (lane == 0) { redf[wave] = sf; redb[wave] = sb; }
    __syncthreads();
    if (tid == 0) {
        atomicAdd(fsum, redf[0] + redf[1] + redf[2] + redf[3]);
        atomicAdd(bsum, redb[0] + redb[1] + redb[2] + redb[3]);
        __threadfence();
        unsigned int c = atomicAdd(counter, 1u);
        isLast = (c == gridDim.x - 1) ? 1 : 0;
        if (isLast) {
            __threadfence();
            float fs = __hip_atomic_load(fsum, __ATOMIC_RELAXED,
                                         __HIP_MEMORY_SCOPE_AGENT);
            float bs = __hip_atomic_load(bsum, __ATOMIC_RELAXED,
                                         __HIP_MEMORY_SCOPE_AGENT);
            out[0] = fs / (float)(BB * MM) + bs / ((float)NN * (float)MM);
        }
    }
}

extern "C" void kernel_launch(void* const* d_in, const int* in_sizes, int n_in,
                              void* d_out, int out_size, void* d_ws, size_t ws_size,
                              hipStream_t stream) {
    const float* x = (const float*)d_in[0];  // (B,N,D)
    const float* y = (const float*)d_in[1];  // (B,M,D)
    float* out = (float*)d_out;

    char* w = (char*)d_ws;
    unsigned char* xq = (unsigned char*)(w);               // 4 MB fp8 (frag order)
    unsigned char* yq = (unsigned char*)(w + 4194304);     // 4 MB fp8, NEGATED
    float*    x2 = (float*)(w + 8388608);                  // 128 KB (x2/2)
    float*    y2 = (float*)(w + 8519680);                  // 128 KB (y2/2)
    unsigned int* fwd = (unsigned int*)(w + 8650752);      // 128 KB (min sq/2)
    float*    bpart = (float*)(w + 8781824);               // 16 KB
    float*    bsum = (float*)(w + 8798208);                // 4 B
    float*    fsum = (float*)(w + 8798212);                // 4 B
    unsigned int* counter = (unsigned int*)(w + 8798216);  // 4 B

    // 65536 rows x 16 threads/row = 1.05M threads
    prep_all<<<(2 * BB * NN * 16) / 256, 256, 0, stream>>>(x, y, xq, yq, x2, y2,
                                                           fwd, bsum, fsum, counter);
    chamfer_main<<<4096, 256, 0, stream>>>(xq, yq, x2, y2, fwd, bpart);
    finalize_kernel<<<32, 256, 0, stream>>>(fwd, bpart, bsum, fsum, counter, out);
}

// Round 2
// 126.189 us; speedup vs baseline: 1.0079x; 1.0079x over previous
//
#include <hip/hip_runtime.h>
#include <hip/hip_fp8.h>

#define BB 8
#define NN 4096
#define MM 4096
#define DD 128

typedef float f32x4  __attribute__((ext_vector_type(4)));
typedef float f32x16 __attribute__((ext_vector_type(16)));
typedef int   i32x4  __attribute__((ext_vector_type(4)));
typedef int   i32x8  __attribute__((ext_vector_type(8)));

// ---------------------------------------------------------------------------
// R21: prep_all rewritten — the old prep issued ONE SCATTERED 8B STORE per
// thread (fragment-ordered layout, stride jumps 2048/1024/8B between
// consecutive threads). 8.4 MB of payload in uncoalesced 8B units explains
// the ~55us gap between bench total (127) and main+finalize (~59).
// New prep: each 256-thread block owns one 32-row group whose fragment data
// is exactly one contiguous 4KB block. Coalesced float4 reads -> cvt ->
// 16B ds_write at the fragment offset -> barrier -> lds[t*16] -> ONE
// coalesced 16B global store per thread. ~42MB of pure coalesced traffic
// (~7us at HBM rate). Fragment-offset math byte-identical to the verified
// layout (absmax 0 in R20).
//
// chamfer_main / finalize UNCHANGED from R20 (passing, absmax 0):
//   - mfma_scale_f32_32x32x64_f8f6f4, identity scale 127
//   - acc seeded with x2/2+y2/2 (y negated in fp8) -> acc = sq/2
//   - R17 balanced XCD patch, fence-free main
// Main is now latency/L2-bound (MfmaUtil 11, VALU 33, HBM 6.7, Occ 34;
// L2 floor ~29us of 56us) — separate round.
//
// LESSONS: merged finalize in main regresses (R11/12/15/16); cooperative
// launch fails (R14); explicit pipelining loses to TLP (R3/4/8/11);
// balanced per-XCD patch keeps working set in 4MB XCD L2 (R17).
// ---------------------------------------------------------------------------

// Prep v2: 2048 blocks x 256 threads. Block g -> 32-row group g.
// Groups 0..1023 = x rows, 1024..2047 = y rows (negated, half-norms).
// Thread t: row r = g*32 + (t>>3), floats [(t&7)*16, +16).
__global__ __launch_bounds__(256)
void prep_all(const float* __restrict__ x, const float* __restrict__ y,
              unsigned char* __restrict__ xq, unsigned char* __restrict__ yq,
              float* __restrict__ x2, float* __restrict__ y2,
              unsigned int* __restrict__ fwd, float* __restrict__ bsum,
              float* __restrict__ fsum, unsigned int* __restrict__ counter) {
    __shared__ i32x4 lbuf[256];  // 4 KB fragment-ordered staging

    const int tid  = threadIdx.x;
    const int g    = blockIdx.x;
    const int gtid = g * 256 + tid;
    if (gtid < BB * MM) fwd[gtid] = 0x7f800000u;  // +inf bits
    if (gtid == 0) { *bsum = 0.0f; *fsum = 0.0f; *counter = 0u; }

    const int rl = tid >> 3;   // row within group (0..31)
    const int c  = tid & 7;    // 16-float chunk within row (0..7)

    const float* src;
    unsigned char* dst;
    float* sq;
    float sgn;
    int row;                   // row within tensor
    if (g < 1024) {
        src = x; dst = xq + (size_t)g * 4096; sq = x2; sgn = 1.0f;
        row = g * 32 + rl;
    } else {
        src = y; dst = yq + (size_t)(g - 1024) * 4096; sq = y2; sgn = -1.0f;
        row = (g - 1024) * 32 + rl;
    }

    const f32x4* base = (const f32x4*)(src + (size_t)row * DD + c * 16);
    f32x4 v[4];
    #pragma unroll
    for (int j = 0; j < 4; ++j) v[j] = base[j];

    float s = 0.0f;
    #pragma unroll
    for (int j = 0; j < 4; ++j)
        s += v[j].x * v[j].x + v[j].y * v[j].y + v[j].z * v[j].z + v[j].w * v[j].w;

    i32x4 d;
    #pragma unroll
    for (int j = 0; j < 4; ++j) {
        unsigned int dj = (unsigned int)__builtin_amdgcn_cvt_pk_fp8_f32(
            sgn * v[j].x, sgn * v[j].y, 0, false);
        dj = (unsigned int)__builtin_amdgcn_cvt_pk_fp8_f32(
            sgn * v[j].z, sgn * v[j].w, (int)dj, true);
        d[j] = (int)dj;
    }

    // fragment offset within the group's 4KB block for k-range [c*16, c*16+16):
    // sub8 = 2c (+1): instr = c>>2, kh = (c>>1)&1, byte-pair (c&1)*16; the two
    // 8B sub-chunks are adjacent -> one 16B unit. Byte i of unit = float c*16+i.
    const int lds_off = (c >> 2) * 2048 + ((c >> 1) & 1) * 1024
                      + rl * 32 + (c & 1) * 16;
    *(i32x4*)((char*)lbuf + lds_off) = d;

    // half-norm reduce across the 8 threads of this row (aligned 8-lane group)
    #pragma unroll
    for (int m = 4; m; m >>= 1) s += __shfl_xor(s, m, 64);
    if (c == 0) sq[row] = 0.5f * s;

    __syncthreads();
    // coalesced flush: thread t writes bytes [t*16, t*16+16) of the 4KB group
    *(i32x4*)(dst + (size_t)tid * 16) = lbuf[tid];
}

// ---------------------------------------------------------------------------
// Main: R17 structure (fence-free, balanced XCD patch), MX MFMA inner loop.
// Accumulator SEEDED with x2/2+y2/2 so acc = sq/2; sq = 2*acc folded into
// the final sqrt sites. UNCHANGED from R20.
// ---------------------------------------------------------------------------
__global__ __launch_bounds__(256, 4)
void chamfer_main(const unsigned char* __restrict__ xq, const unsigned char* __restrict__ yq,
                  const float* __restrict__ x2, const float* __restrict__ y2,
                  unsigned int* __restrict__ fwd, float* __restrict__ bpart) {
    __shared__ float x2s[BB][128];          // 4 KB (half-norms)
    __shared__ float y2s[BB][32];           // 1 KB (half-norms)
    __shared__ unsigned int fbuf[BB][32];   // 1 KB (min sq/2 bits)
    __shared__ float red[4];

    const int tid   = threadIdx.x;
    const int lane  = tid & 63;
    const int wave  = tid >> 6;
    const int lhalf = lane >> 5;   // K-half for operand frags; +4 row off for C/D
    const int l31   = lane & 31;

    const int id  = blockIdx.x;
    const int xcd = id & 7;
    const int j   = id >> 3;                  // 0..511
    const int nb  = (xcd >> 1) * 8 + (j & 7); // 0..31 (128 n each)
    const int mb  = (xcd & 1) * 64 + (j >> 3);// 0..127 (32 m each)
    const int n0b = nb * 128;
    const int n0w = n0b + wave * 32;
    const int m0  = mb * 32;

    // operand fragment base: group*4096 + (lane>>5)*1024 + (lane&31)*32
    const size_t laneoff = (size_t)lhalf * 1024 + (size_t)l31 * 32;
    const unsigned char* xbase = xq + (size_t)(n0w >> 5) * 4096 + laneoff;
    const unsigned char* ybase = yq + (size_t)mb * 4096 + laneoff;

    for (int i = tid; i < BB * 128; i += 256)
        x2s[i >> 7][i & 127] = x2[(size_t)(i >> 7) * NN + n0b + (i & 127)];
    if (tid < BB * 32) {
        y2s[tid >> 5][tid & 31] = y2[(size_t)(tid >> 5) * MM + m0 + (tid & 31)];
        ((unsigned int*)fbuf)[tid] = 0x7f800000u;
    }
    __syncthreads();

    i32x4 fx[2][2][2], fy[2][2][2];  // [buf][instr(K64)][16B half]
    auto loadb = [&](int b, int s) {
        const unsigned char* xb = xbase + ((size_t)b << 19);  // b*128 groups*4KB
        const unsigned char* yb = ybase + ((size_t)b << 19);
        #pragma unroll
        for (int i = 0; i < 2; ++i)
            #pragma unroll
            for (int hh = 0; hh < 2; ++hh) {
                fx[s][i][hh] = *(const i32x4*)(xb + i * 2048 + hh * 16);
                fy[s][i][hh] = *(const i32x4*)(yb + i * 2048 + hh * 16);
            }
    };
    loadb(0, 0);

    const float INF = __builtin_inff();
    float bmin[16];  // running min of acc = sq/2 over batches
    #pragma unroll
    for (int r = 0; r < 16; ++r) bmin[r] = INF;

    #pragma unroll 2
    for (int b = 0; b < BB; ++b) {
        const int cur = b & 1;
        if (b < BB - 1) loadb(b + 1, cur ^ 1);  // the ONLY vmem in the loop

        // seed acc with (x2+y2)/2 -> MFMA (with -y fp8) yields acc = sq/2
        // C/D: col = l31, row = (r&3) + 8*(r>>2) + 4*lhalf
        float y2v = y2s[b][l31];
        f32x16 acc;
        #pragma unroll
        for (int q = 0; q < 4; ++q) {
            f32x4 xv = *(const f32x4*)&x2s[b][wave * 32 + lhalf * 4 + q * 8];
            #pragma unroll
            for (int e = 0; e < 4; ++e)
                acc[q * 4 + e] = xv[e] + y2v;
        }

        #pragma unroll
        for (int i = 0; i < 2; ++i) {
            i32x8 av = __builtin_shufflevector(fx[cur][i][0], fx[cur][i][1],
                                               0, 1, 2, 3, 4, 5, 6, 7);
            i32x8 bv = __builtin_shufflevector(fy[cur][i][0], fy[cur][i][1],
                                               0, 1, 2, 3, 4, 5, 6, 7);
            // fmt 0 = fp8 e4m3 for A and B; E8M0 scale 127 -> 2^0 = 1.0
            acc = __builtin_amdgcn_mfma_scale_f32_32x32x64_f8f6f4(
                av, bv, acc, 0, 0, 0, 127, 0, 127);
        }

        // epilogue: pure fmin (acc IS sq/2); one fwd atomic per lane
        float fm = INF;
        #pragma unroll
        for (int r = 0; r < 16; ++r) {
            bmin[r] = fminf(bmin[r], acc[r]);
            fm      = fminf(fm, acc[r]);
        }
        // clamp >=0 so uint ordering == float ordering; lanes l/l+32 share
        // an address (2-way): no-return ds_min, pipelined
        atomicMin(&fbuf[b][l31], __float_as_uint(fmaxf(fm, 0.0f)));
    }
    __syncthreads();

    // flush forward mins (values are sq/2; finalize applies the 2x)
    {
        int b = tid >> 5, c = tid & 31;
        atomicMin(&fwd[(size_t)b * MM + m0 + c], fbuf[b][c]);
    }

    // backward: sqrt(2 * clamp(min sq/2)), block-reduce, one store/block
    float s = 0.0f;
    #pragma unroll
    for (int r = 0; r < 16; ++r)
        s += sqrtf(2.0f * fmaxf(bmin[r], 0.0f));
    #pragma unroll
    for (int off = 32; off; off >>= 1) s += __shfl_down(s, off, 64);
    if (lane == 0) red[wave] = s;
    __syncthreads();
    if (tid == 0) bpart[id] = red[0] + red[1] + red[2] + red[3];
}

// Finalize: 32 blocks x 256 threads (fences live here, paid 32x not 4096x).
// fwd holds min sq/2 -> dist = sqrt(2*v).
__global__ __launch_bounds__(256)
void finalize_kernel(const unsigned int* __restrict__ fwd,
                     const float* __restrict__ bpart,
                     float* __restrict__ bsum, float* __restrict__ fsum,
                     unsigned int* __restrict__ counter, float* __restrict__ out) {
    __shared__ float redf[4], redb[4];
    __shared__ int isLast;
    const int tid = threadIdx.x, lane = tid & 63, wave = tid >> 6;
    const int gtid = blockIdx.x * 256 + tid;
    uint4 u = ((const uint4*)fwd)[gtid];
    float sf = sqrtf(2.0f * __uint_as_float(u.x)) + sqrtf(2.0f * __uint_as_float(u.y)) +
               sqrtf(2.0f * __uint_as_float(u.z)) + sqrtf(2.0f * __uint_as_float(u.w));
    float sb = (gtid < 4096) ? bpart[gtid] : 0.0f;
    #pragma unroll
    for (int off = 32; off; off >>= 1) {
        sf += __shfl_down(sf, off, 64);
        sb += __shfl_down(sb, off, 64);
    }
    if (lane == 0) { redf[wave] = sf; redb[wave] = sb; }
    __syncthreads();
    if (tid == 0) {
        atomicAdd(fsum, redf[0] + redf[1] + redf[2] + redf[3]);
        atomicAdd(bsum, redb[0] + redb[1] + redb[2] + redb[3]);
        __threadfence();
        unsigned int c = atomicAdd(counter, 1u);
        isLast = (c == gridDim.x - 1) ? 1 : 0;
        if (isLast) {
            __threadfence();
            float fs = __hip_atomic_load(fsum, __ATOMIC_RELAXED,
                                         __HIP_MEMORY_SCOPE_AGENT);
            float bs = __hip_atomic_load(bsum, __ATOMIC_RELAXED,
                                         __HIP_MEMORY_SCOPE_AGENT);
            out[0] = fs / (float)(BB * MM) + bs / ((float)NN * (float)MM);
        }
    }
}

extern "C" void kernel_launch(void* const* d_in, const int* in_sizes, int n_in,
                              void* d_out, int out_size, void* d_ws, size_t ws_size,
                              hipStream_t stream) {
    const float* x = (const float*)d_in[0];  // (B,N,D)
    const float* y = (const float*)d_in[1];  // (B,M,D)
    float* out = (float*)d_out;

    char* w = (char*)d_ws;
    unsigned char* xq = (unsigned char*)(w);               // 4 MB fp8 (frag order)
    unsigned char* yq = (unsigned char*)(w + 4194304);     // 4 MB fp8, NEGATED
    float*    x2 = (float*)(w + 8388608);                  // 128 KB (x2/2)
    float*    y2 = (float*)(w + 8519680);                  // 128 KB (y2/2)
    unsigned int* fwd = (unsigned int*)(w + 8650752);      // 128 KB (min sq/2)
    float*    bpart = (float*)(w + 8781824);               // 16 KB
    float*    bsum = (float*)(w + 8798208);                // 4 B
    float*    fsum = (float*)(w + 8798212);                // 4 B
    unsigned int* counter = (unsigned int*)(w + 8798216);  // 4 B

    // 2048 blocks: one 32-row fragment group (4KB) per block
    prep_all<<<2048, 256, 0, stream>>>(x, y, xq, yq, x2, y2,
                                       fwd, bsum, fsum, counter);
    chamfer_main<<<4096, 256, 0, stream>>>(xq, yq, x2, y2, fwd, bpart);
    finalize_kernel<<<32, 256, 0, stream>>>(fwd, bpart, bsum, fsum, counter, out);
}

// Round 3
// 116.767 us; speedup vs baseline: 1.0892x; 1.0807x over previous
//
#include <hip/hip_runtime.h>
#include <hip/hip_fp8.h>

#define BB 8
#define NN 4096
#define MM 4096
#define DD 128

typedef float f32x4  __attribute__((ext_vector_type(4)));
typedef float f32x16 __attribute__((ext_vector_type(16)));
typedef int   i32x4  __attribute__((ext_vector_type(4)));
typedef int   i32x8  __attribute__((ext_vector_type(8)));

// ---------------------------------------------------------------------------
// R22: cut chamfer_main's L2 traffic 2.7x. Evidence: main=56us with MfmaUtil
// 11 (matrix floor 7.3us), VALU 33 (~18.5us), HBM 6.6 -> the 1.07GB of L2
// reads (31us at ceiling) dominates. The 4 waves of a block all read the
// SAME y-frags (4x redundant), and m-extent per wave was only 32.
// New shape: block = 128n x 64m (2048 blocks), wave = 32n x 64m.
//   - y-frags (8KB/batch, contiguous in global thanks to prep's layout) are
//     staged ONCE per block into LDS via global_load_lds width=16,
//     double-buffered, one barrier per batch.
//   - LDS y layout is DENSIFIED for conflict-free ds_read_b128: the
//     permutation is applied on the per-lane GLOBAL SOURCE address (rule:
//     gload_lds writes wave-uniform base + lane*16 linearly), read side uses
//     matching dense offsets (lane-stride 16B).
//   - x-frags stay in per-wave registers (distinct n per wave), dbuf.
// Traffic: x 256MB + y 131MB = 390MB (was 1071MB) -> L2 floor ~11us; VALU
// floor ~18.5us becomes the cap. Prediction: main 56 -> ~30us.
//
// R19-21 retained: fragment-ordered fp8 (absmax 0), HALF-norms + negated y
// so MFMA acc = sq/2, mfma_scale_f32_32x32x64_f8f6f4 identity-scale 127,
// balanced per-XCD patch (3MB < 4MB XCD L2), coalesced prep.
// LESSONS: merged finalize regresses (R11/12/15/16); cooperative launch
// fails (R14); prep transport is NOT the total-time gap (R21: -1us).
// ---------------------------------------------------------------------------

typedef const __attribute__((address_space(1))) unsigned int* gas_ptr;
typedef __attribute__((address_space(3))) unsigned int* las_ptr;
static __device__ __forceinline__ void gload_lds16(const unsigned char* g,
                                                   unsigned char* l) {
    __builtin_amdgcn_global_load_lds((gas_ptr)g, (las_ptr)l, 16, 0, 0);
}

// Prep v2 (R21, unchanged): 2048 blocks x 256 threads, one 32-row fragment
// group (4KB) per block; coalesced reads -> cvt -> LDS permute -> coalesced
// 16B stores. Also inits fwd/bsum/fsum/counter and writes half-norms.
__global__ __launch_bounds__(256)
void prep_all(const float* __restrict__ x, const float* __restrict__ y,
              unsigned char* __restrict__ xq, unsigned char* __restrict__ yq,
              float* __restrict__ x2, float* __restrict__ y2,
              unsigned int* __restrict__ fwd, float* __restrict__ bsum,
              float* __restrict__ fsum, unsigned int* __restrict__ counter) {
    __shared__ i32x4 lbuf[256];  // 4 KB fragment-ordered staging

    const int tid  = threadIdx.x;
    const int g    = blockIdx.x;
    const int gtid = g * 256 + tid;
    if (gtid < BB * MM) fwd[gtid] = 0x7f800000u;  // +inf bits
    if (gtid == 0) { *bsum = 0.0f; *fsum = 0.0f; *counter = 0u; }

    const int rl = tid >> 3;   // row within group (0..31)
    const int c  = tid & 7;    // 16-float chunk within row (0..7)

    const float* src;
    unsigned char* dst;
    float* sq;
    float sgn;
    int row;
    if (g < 1024) {
        src = x; dst = xq + (size_t)g * 4096; sq = x2; sgn = 1.0f;
        row = g * 32 + rl;
    } else {
        src = y; dst = yq + (size_t)(g - 1024) * 4096; sq = y2; sgn = -1.0f;
        row = (g - 1024) * 32 + rl;
    }

    const f32x4* base = (const f32x4*)(src + (size_t)row * DD + c * 16);
    f32x4 v[4];
    #pragma unroll
    for (int j = 0; j < 4; ++j) v[j] = base[j];

    float s = 0.0f;
    #pragma unroll
    for (int j = 0; j < 4; ++j)
        s += v[j].x * v[j].x + v[j].y * v[j].y + v[j].z * v[j].z + v[j].w * v[j].w;

    i32x4 d;
    #pragma unroll
    for (int j = 0; j < 4; ++j) {
        unsigned int dj = (unsigned int)__builtin_amdgcn_cvt_pk_fp8_f32(
            sgn * v[j].x, sgn * v[j].y, 0, false);
        dj = (unsigned int)__builtin_amdgcn_cvt_pk_fp8_f32(
            sgn * v[j].z, sgn * v[j].w, (int)dj, true);
        d[j] = (int)dj;
    }

    const int lds_off = (c >> 2) * 2048 + ((c >> 1) & 1) * 1024
                      + rl * 32 + (c & 1) * 16;
    *(i32x4*)((char*)lbuf + lds_off) = d;

    #pragma unroll
    for (int m = 4; m; m >>= 1) s += __shfl_xor(s, m, 64);
    if (c == 0) sq[row] = 0.5f * s;

    __syncthreads();
    *(i32x4*)(dst + (size_t)tid * 16) = lbuf[tid];
}

// ---------------------------------------------------------------------------
// Main v3: 2048 blocks (128n x 64m each), 4 waves of 32n x 64m.
// ---------------------------------------------------------------------------
__global__ __launch_bounds__(256, 3)
void chamfer_main(const unsigned char* __restrict__ xq, const unsigned char* __restrict__ yq,
                  const float* __restrict__ x2, const float* __restrict__ y2,
                  unsigned int* __restrict__ fwd, float* __restrict__ bpart) {
    __shared__ float x2s[BB][128];            // 4 KB
    __shared__ float y2s[BB][64];             // 2 KB
    __shared__ unsigned int fbuf[BB][64];     // 2 KB
    __shared__ unsigned char ybuf[2][8192];   // 16 KB y-frag double buffer
    __shared__ float red[4];

    const int tid   = threadIdx.x;
    const int lane  = tid & 63;
    const int wave  = tid >> 6;
    const int lhalf = lane >> 5;
    const int l31   = lane & 31;

    const int id  = blockIdx.x;
    const int xcd = id & 7;
    const int j   = id >> 3;                   // 0..255
    const int nb  = (xcd >> 1) * 8 + (j & 7);  // 0..31  (128 n each)
    const int mb  = (xcd & 1) * 32 + (j >> 3); // 0..63  (64 m each)
    const int n0b = nb * 128;
    const int n0w = n0b + wave * 32;
    const int m0  = mb * 64;

    // x fragment base (per-wave registers, as in R20/21)
    const size_t laneoff = (size_t)lhalf * 1024 + (size_t)l31 * 32;
    const unsigned char* xbase = xq + (size_t)(n0w >> 5) * 4096 + laneoff;

    // y: global base for batch b is yq + (b*128 + 2*mb)*4096 (two contiguous
    // 4KB groups). Stage via gload_lds with SOURCE swizzle so LDS is dense:
    // LDS unit U (16B) = i*128 + lhalf*64 + hh*32 + l31 holds global frag
    // byte a = i*2048 + lhalf*1024 + l31*32 + hh*16. Wave w stages chunks w
    // (group 0) and w+4 (group 1); per-lane source offset:
    const size_t ysw = (size_t)(wave >> 1) * 2048 + (size_t)(wave & 1) * 1024
                     + ((size_t)lhalf << 4) + (size_t)l31 * 32;
    const unsigned char* ybase = yq + (size_t)(2 * mb) * 4096 + ysw;
    const int rb0 = l31 * 16 + lhalf * 1024;  // dense read base

    auto stage_y = [&](int b, int s) {
        const unsigned char* gsrc = ybase + ((size_t)b << 19);
        gload_lds16(gsrc,        &ybuf[s][wave * 1024]);
        gload_lds16(gsrc + 4096, &ybuf[s][4096 + wave * 1024]);
    };

    i32x4 fx[2][2][2];  // [buf][instr(K64)][16B half]
    auto loadx = [&](int b, int s) {
        const unsigned char* xb = xbase + ((size_t)b << 19);
        #pragma unroll
        for (int i = 0; i < 2; ++i)
            #pragma unroll
            for (int hh = 0; hh < 2; ++hh)
                fx[s][i][hh] = *(const i32x4*)(xb + i * 2048 + hh * 16);
    };

    // prologue: issue batch-0 staging, then LDS init, one barrier
    stage_y(0, 0);
    loadx(0, 0);
    for (int i = tid; i < BB * 128; i += 256)
        x2s[i >> 7][i & 127] = x2[(size_t)(i >> 7) * NN + n0b + (i & 127)];
    for (int i = tid; i < BB * 64; i += 256) {
        y2s[i >> 6][i & 63] = y2[(size_t)(i >> 6) * MM + m0 + (i & 63)];
        ((unsigned int*)fbuf)[i] = 0x7f800000u;
    }
    __syncthreads();

    const float INF = __builtin_inff();
    float bmin[2][16];  // [m-tile][reg] running min of acc = sq/2
    #pragma unroll
    for (int t = 0; t < 2; ++t)
        #pragma unroll
        for (int r = 0; r < 16; ++r) bmin[t][r] = INF;

    #pragma unroll 2
    for (int b = 0; b < BB; ++b) {
        const int cur = b & 1;
        if (b < BB - 1) {
            stage_y(b + 1, cur ^ 1);   // async into other LDS buffer
            loadx(b + 1, cur ^ 1);     // regs, dbuf
        }

        // acc seeds: (x2+y2)/2 -> MFMA (neg-y fp8) yields acc = sq/2
        float y2v[2];
        y2v[0] = y2s[b][l31];
        y2v[1] = y2s[b][32 + l31];
        f32x16 acc[2];
        #pragma unroll
        for (int q = 0; q < 4; ++q) {
            f32x4 xv = *(const f32x4*)&x2s[b][wave * 32 + lhalf * 4 + q * 8];
            #pragma unroll
            for (int t = 0; t < 2; ++t)
                #pragma unroll
                for (int e = 0; e < 4; ++e)
                    acc[t][q * 4 + e] = xv[e] + y2v[t];
        }

        #pragma unroll
        for (int i = 0; i < 2; ++i) {
            i32x8 av = __builtin_shufflevector(fx[cur][i][0], fx[cur][i][1],
                                               0, 1, 2, 3, 4, 5, 6, 7);
            #pragma unroll
            for (int t = 0; t < 2; ++t) {
                const unsigned char* yb = &ybuf[cur][t * 4096 + i * 2048 + rb0];
                i32x4 lo = *(const i32x4*)(yb);
                i32x4 hi = *(const i32x4*)(yb + 512);
                i32x8 bv = __builtin_shufflevector(lo, hi, 0, 1, 2, 3, 4, 5, 6, 7);
                acc[t] = __builtin_amdgcn_mfma_scale_f32_32x32x64_f8f6f4(
                    av, bv, acc[t], 0, 0, 0, 127, 0, 127);
            }
        }

        // epilogue: pure fmin (acc IS sq/2)
        float fm[2] = {INF, INF};
        #pragma unroll
        for (int t = 0; t < 2; ++t)
            #pragma unroll
            for (int r = 0; r < 16; ++r) {
                bmin[t][r] = fminf(bmin[t][r], acc[t][r]);
                fm[t]      = fminf(fm[t], acc[t][r]);
            }
        #pragma unroll
        for (int t = 0; t < 2; ++t)
            atomicMin(&fbuf[b][t * 32 + l31],
                      __float_as_uint(fmaxf(fm[t], 0.0f)));

        __syncthreads();  // ybuf[cur^1] staged; ybuf[cur] reads done
    }

    // flush forward mins (values are sq/2; finalize applies the 2x)
    for (int i = tid; i < BB * 64; i += 256)
        atomicMin(&fwd[(size_t)(i >> 6) * MM + m0 + (i & 63)], fbuf[i >> 6][i & 63]);

    // backward: sqrt(2 * clamp(min sq/2)), block-reduce, one store/block
    float s = 0.0f;
    #pragma unroll
    for (int t = 0; t < 2; ++t)
        #pragma unroll
        for (int r = 0; r < 16; ++r)
            s += sqrtf(2.0f * fmaxf(bmin[t][r], 0.0f));
    #pragma unroll
    for (int off = 32; off; off >>= 1) s += __shfl_down(s, off, 64);
    if (lane == 0) red[wave] = s;
    __syncthreads();
    if (tid == 0) bpart[id] = red[0] + red[1] + red[2] + red[3];
}

// Finalize: 32 blocks x 256 threads. fwd holds min sq/2 -> dist = sqrt(2v).
__global__ __launch_bounds__(256)
void finalize_kernel(const unsigned int* __restrict__ fwd,
                     const float* __restrict__ bpart,
                     float* __restrict__ bsum, float* __restrict__ fsum,
                     unsigned int* __restrict__ counter, float* __restrict__ out) {
    __shared__ float redf[4], redb[4];
    __shared__ int isLast;
    const int tid = threadIdx.x, lane = tid & 63, wave = tid >> 6;
    const int gtid = blockIdx.x * 256 + tid;
    uint4 u = ((const uint4*)fwd)[gtid];
    float sf = sqrtf(2.0f * __uint_as_float(u.x)) + sqrtf(2.0f * __uint_as_float(u.y)) +
               sqrtf(2.0f * __uint_as_float(u.z)) + sqrtf(2.0f * __uint_as_float(u.w));
    float sb = (gtid < 2048) ? bpart[gtid] : 0.0f;   // 2048 main blocks now
    #pragma unroll
    for (int off = 32; off; off >>= 1) {
        sf += __shfl_down(sf, off, 64);
        sb += __shfl_down(sb, off, 64);
    }
    if (lane == 0) { redf[wave] = sf; redb[wave] = sb; }
    __syncthreads();
    if (tid == 0) {
        atomicAdd(fsum, redf[0] + redf[1] + redf[2] + redf[3]);
        atomicAdd(bsum, redb[0] + redb[1] + redb[2] + redb[3]);
        __threadfence();
        unsigned int c = atomicAdd(counter, 1u);
        isLast = (c == gridDim.x - 1) ? 1 : 0;
        if (isLast) {
            __threadfence();
            float fs = __hip_atomic_load(fsum, __ATOMIC_RELAXED,
                                         __HIP_MEMORY_SCOPE_AGENT);
            float bs = __hip_atomic_load(bsum, __ATOMIC_RELAXED,
                                         __HIP_MEMORY_SCOPE_AGENT);
            out[0] = fs / (float)(BB * MM) + bs / ((float)NN * (float)MM);
        }
    }
}

extern "C" void kernel_launch(void* const* d_in, const int* in_sizes, int n_in,
                              void* d_out, int out_size, void* d_ws, size_t ws_size,
                              hipStream_t stream) {
    const float* x = (const float*)d_in[0];  // (B,N,D)
    const float* y = (const float*)d_in[1];  // (B,M,D)
    float* out = (float*)d_out;

    char* w = (char*)d_ws;
    unsigned char* xq = (unsigned char*)(w);               // 4 MB fp8 (frag order)
    unsigned char* yq = (unsigned char*)(w + 4194304);     // 4 MB fp8, NEGATED
    float*    x2 = (float*)(w + 8388608);                  // 128 KB (x2/2)
    float*    y2 = (float*)(w + 8519680);                  // 128 KB (y2/2)
    unsigned int* fwd = (unsigned int*)(w + 8650752);      // 128 KB (min sq/2)
    float*    bpart = (float*)(w + 8781824);               // 8 KB (2048 blocks)
    float*    bsum = (float*)(w + 8798208);                // 4 B
    float*    fsum = (float*)(w + 8798212);                // 4 B
    unsigned int* counter = (unsigned int*)(w + 8798216);  // 4 B

    prep_all<<<2048, 256, 0, stream>>>(x, y, xq, yq, x2, y2,
                                       fwd, bsum, fsum, counter);
    chamfer_main<<<2048, 256, 0, stream>>>(xq, yq, x2, y2, fwd, bpart);
    finalize_kernel<<<32, 256, 0, stream>>>(fwd, bpart, bsum, fsum, counter, out);
}